// Round 4
// baseline (540.344 us; speedup 1.0000x reference)
//
#include <hip/hip_runtime.h>
#include <stdint.h>

#define HIDDEN 512
#define ONEHOT 64
#define EDIM   576   // HIDDEN + ONEHOT
#define BATCH  128
#define LSEQ   1024
#define FANIN  1088  // 2*HIDDEN + ONEHOT

typedef __attribute__((ext_vector_type(8))) short short8;
typedef __attribute__((ext_vector_type(4))) float f32x4;

__device__ inline unsigned short f2bf(float x) {
    union { float f; unsigned int u; } v; v.f = x;
    unsigned int u = v.u;
    unsigned int r = (u + 0x7FFFu + ((u >> 16) & 1u)) >> 16;  // RNE
    return (unsigned short)r;
}

__device__ inline float fast_tanh(float x) {
    float ax = fabsf(x);
    float e  = __expf(2.f * ax);
    float t  = 1.f - __fdividef(2.f, e + 1.f);
    return copysignf(t, x);
}

// ---- prep: part_h[b][h] = hidden.W[:, :512]^T + bias  AND  We -> bf16 -----
// WeB layout: [kc 9][h 512][g' 8][j 8], where the element stored at group g'
// is logical k = (g' ^ (h&7))*8 + j  -- XOR swizzle so the LDS image
// (loaded via global_load_lds, lane*16B order) has conflict-free frag reads.
__global__ __launch_bounds__(256) void k_prep(const float* __restrict__ hidden,
                                              const float* __restrict__ W,
                                              const float* __restrict__ bias,
                                              float* __restrict__ ph,
                                              unsigned short* __restrict__ WeB) {
    int bid = blockIdx.x;
    int tid = threadIdx.x;
    if (bid < 256) {
        int gid = bid * 256 + tid;                 // 65536 threads
        int b = gid & (BATCH - 1);
        int h = gid >> 7;
        const float* hrow = hidden + b * HIDDEN;
        const float* wrow = W + h * FANIN;
        float acc = 0.f;
#pragma unroll 4
        for (int d = 0; d < HIDDEN; d += 4) {
            float4 hv = *(const float4*)(hrow + d);
            float4 wv = *(const float4*)(wrow + d);
            acc += hv.x * wv.x + hv.y * wv.y + hv.z * wv.z + hv.w * wv.w;
        }
        ph[b * HIDDEN + h] = acc + bias[h];
    } else {
        int i = (bid - 256) * 256 + tid;           // 0..294911
        int kc = i >> 15;                          // 0..8
        int h  = (i >> 6) & 511;
        int g  = (i >> 3) & 7;                     // physical 16B group
        int j  = i & 7;
        int k  = ((g ^ (h & 7)) << 3) | j;         // logical k in chunk
        WeB[i] = f2bf(W[h * FANIN + HIDDEN + kc * 64 + k]);
    }
}

// ---- main fused GEMM + tanh + v-dot ---------------------------------------
// 512 thr = 8 waves (4 vm x 2 vn), wave tile 32m x 64n. Block tile: M=128
// (all b of one l) x N=128 h. Grid: 1D 4096, swizzled so the 4 blocks sharing
// one enc A-tile (same l, ht=0..3) have IDs spaced 8 apart -> same XCD under
// round-robin id%8 assignment (and still a compact window under linear fill).
__global__ __launch_bounds__(512) void k_main(
        const float* __restrict__ enc,            // [L][B][EDIM] fp32
        const unsigned short* __restrict__ WeB,   // swizzled [9][512][64] bf16
        const float* __restrict__ ph,             // [B][HIDDEN] (bias included)
        const float* __restrict__ v,
        float* __restrict__ scoresP)              // [8 slots][L][B] partials
{
    __shared__ unsigned short aLds[128 * 64];     // 16384 B dense, swizzled
    __shared__ unsigned short bLds[128 * 64];     // 16384 B dense, swizzled

    const int tid  = threadIdx.x;
    const int wave = tid >> 6;
    const int lane = tid & 63;
    const int c  = lane & 15;
    const int q  = lane >> 4;
    const int vm = wave & 3;      // m quadrant (32 rows)
    const int vn = wave >> 2;     // n half (64 cols)

    const int id = blockIdx.x;
    const int ht = (id >> 3) & 3;                 // h-tile 0..3
    const int l  = (id & 7) + ((id >> 5) << 3);   // 0..1023
    const int hbase = ht * 128;

    f32x4 acc[2][4];
#pragma unroll
    for (int i = 0; i < 2; ++i)
#pragma unroll
        for (int j = 0; j < 4; ++j) acc[i][j] = (f32x4){0.f, 0.f, 0.f, 0.f};

    const float* abase = enc + (size_t)l * (BATCH * EDIM);
    const char*  bsrc  = (const char*)WeB + (size_t)ht * 16384;

    for (int kc = 0; kc < 9; ++kc) {
        // A global loads (fp32): 2 x (row, 8-elem group) per thread
        float4 av[2][2];
#pragma unroll
        for (int p = 0; p < 2; ++p) {
            int idx = p * 512 + tid;              // 0..1023 over 128x(8 groups)
            int row = idx >> 3;
            int g   = idx & 7;
            const float* src = abase + row * EDIM + kc * 64 + g * 8;
            av[p][0] = *(const float4*)src;
            av[p][1] = *(const float4*)(src + 4);
        }

        __syncthreads();   // previous iteration's LDS reads complete

        // B tile: async DMA global->LDS, 16 B/lane, dense image
#pragma unroll
        for (int p = 0; p < 2; ++p) {
            int off = p * 8192 + wave * 1024;
            __builtin_amdgcn_global_load_lds(
                (const __attribute__((address_space(1))) unsigned int*)
                    (bsrc + (size_t)kc * 65536 + off + lane * 16),
                (__attribute__((address_space(3))) unsigned int*)
                    ((char*)bLds + off),
                16, 0, 0);
        }

        // A: fp32 -> bf16 -> LDS, dense 128B rows, 16B-group XOR swizzle
#pragma unroll
        for (int p = 0; p < 2; ++p) {
            int idx = p * 512 + tid;
            int row = idx >> 3;
            int g   = idx & 7;
            int gp  = g ^ (row & 7);
            short8 w;
            w[0] = (short)f2bf(av[p][0].x); w[1] = (short)f2bf(av[p][0].y);
            w[2] = (short)f2bf(av[p][0].z); w[3] = (short)f2bf(av[p][0].w);
            w[4] = (short)f2bf(av[p][1].x); w[5] = (short)f2bf(av[p][1].y);
            w[6] = (short)f2bf(av[p][1].z); w[7] = (short)f2bf(av[p][1].w);
            *(short8*)((char*)aLds + row * 128 + gp * 16) = w;
        }

        __syncthreads();   // waits vmcnt(0) (B DMA) + lgkm (A writes)

#pragma unroll
        for (int kk = 0; kk < 2; ++kk) {
            short8 af[2], bf[4];
#pragma unroll
            for (int am = 0; am < 2; ++am) {
                int mrow = vm * 32 + am * 16 + c;
                int g    = ((kk << 2) | q) ^ (c & 7);
                af[am] = *(const short8*)((const char*)aLds + mrow * 128 + g * 16);
            }
#pragma unroll
            for (int an = 0; an < 4; ++an) {
                int row = vn * 64 + an * 16 + c;
                int g   = ((kk << 2) | q) ^ (c & 7);
                bf[an]  = *(const short8*)((const char*)bLds + row * 128 + g * 16);
            }
#pragma unroll
            for (int am = 0; am < 2; ++am)
#pragma unroll
                for (int an = 0; an < 4; ++an)
                    acc[am][an] = __builtin_amdgcn_mfma_f32_16x16x32_bf16(
                        af[am], bf[an], acc[am][an], 0, 0, 0);
        }
    }

    // ---- epilogue: tanh, v-dot, reduce over 16 c-lanes, slot store --------
    float vv[4];
#pragma unroll
    for (int an = 0; an < 4; ++an) vv[an] = v[hbase + vn * 64 + an * 16 + c];

    const int slot = ht * 2 + vn;
#pragma unroll
    for (int am = 0; am < 2; ++am) {
#pragma unroll
        for (int r = 0; r < 4; ++r) {
            int b = vm * 32 + am * 16 + q * 4 + r;
            const float* phr = ph + b * HIDDEN + hbase + vn * 64 + c;
            float s = 0.f;
#pragma unroll
            for (int an = 0; an < 4; ++an) {
                float e = acc[am][an][r] + phr[an * 16];
                s += vv[an] * fast_tanh(e);
            }
            s += __shfl_xor(s, 1);
            s += __shfl_xor(s, 2);
            s += __shfl_xor(s, 4);
            s += __shfl_xor(s, 8);
            if (c == 0)
                scoresP[((size_t)slot * LSEQ + l) * BATCH + b] = s;
        }
    }
}

// ---- softmax over L per batch row; sums the 8 partial slots ---------------
__global__ __launch_bounds__(256) void k_softmax(const float* __restrict__ sp,
                                                 float* __restrict__ out) {
    __shared__ float red[4];
    int b = blockIdx.x;
    int tid = threadIdx.x;
    float vals[4];
#pragma unroll
    for (int i = 0; i < 4; ++i) {
        int li = tid + i * 256;
        float s = 0.f;
#pragma unroll
        for (int sl = 0; sl < 8; ++sl)
            s += sp[((size_t)sl * LSEQ + li) * BATCH + b];
        vals[i] = s;
    }

    float m = fmaxf(fmaxf(vals[0], vals[1]), fmaxf(vals[2], vals[3]));
    for (int off = 1; off < 64; off <<= 1) m = fmaxf(m, __shfl_xor(m, off));
    int wv = tid >> 6;
    if ((tid & 63) == 0) red[wv] = m;
    __syncthreads();
    m = fmaxf(fmaxf(red[0], red[1]), fmaxf(red[2], red[3]));
    __syncthreads();

    float sum = 0.f;
#pragma unroll
    for (int i = 0; i < 4; ++i) { vals[i] = __expf(vals[i] - m); sum += vals[i]; }
    for (int off = 1; off < 64; off <<= 1) sum += __shfl_xor(sum, off);
    if ((tid & 63) == 0) red[wv] = sum;
    __syncthreads();
    sum = red[0] + red[1] + red[2] + red[3];
    float inv = 1.f / sum;
#pragma unroll
    for (int i = 0; i < 4; ++i)
        out[(size_t)b * LSEQ + tid + i * 256] = vals[i] * inv;
}

extern "C" void kernel_launch(void* const* d_in, const int* in_sizes, int n_in,
                              void* d_out, int out_size, void* d_ws, size_t ws_size,
                              hipStream_t stream) {
    const float* hidden = (const float*)d_in[0];   // [128][512]
    const float* enc    = (const float*)d_in[1];   // [1024][128][576]
    const float* W      = (const float*)d_in[2];   // [512][1088]
    const float* bias   = (const float*)d_in[3];   // [512]
    const float* v      = (const float*)d_in[4];   // [512]
    float* out = (float*)d_out;                    // [128][1][1024]

    char* ws = (char*)d_ws;
    float* ph           = (float*)ws;                       // 256 KB
    unsigned short* WeB = (unsigned short*)(ws + 262144);   // 576 KB
    float* scoresP      = (float*)(ws + 851968);            // 4 MB [8][L][B]

    hipLaunchKernelGGL(k_prep, dim3(1408), dim3(256), 0, stream,
                       hidden, W, bias, ph, WeB);
    hipLaunchKernelGGL(k_main, dim3(4096), dim3(512), 0, stream,
                       enc, WeB, ph, v, scoresP);
    hipLaunchKernelGGL(k_softmax, dim3(128), dim3(256), 0, stream, scoresP, out);
}